// Round 9
// baseline (1464.909 us; speedup 1.0000x reference)
//
#include <hip/hip_runtime.h>
#include <stdint.h>

#define B_ 1024
#define F_ 4
#define M_ 512
#define D_ 8192
#define ITERS_ 10
#define DW_ 128      // D/64 u64 words per D-vector
#define SMSZ2 32768  // one staging buffer: Aq 8K + Ar 8K + B 16K

typedef unsigned long long u64;
typedef unsigned int u32;
typedef unsigned short u16;
typedef signed char i8;

typedef int i32x4 __attribute__((ext_vector_type(4)));
typedef u64 u64x2 __attribute__((ext_vector_type(2)));

struct Flags { u32 done; u32 k; u32 conv[ITERS_]; };

__device__ inline void gload_lds16(const void* g, void* l){
  __builtin_amdgcn_global_load_lds(
      (const __attribute__((address_space(1))) void*)g,
      (__attribute__((address_space(3))) void*)l, 16, 0, 0);
}

__device__ inline bool conv_prefix_done(const u32* conv, int iter){
  bool d = false;
  for (int j = 0; j < iter; ++j) d |= (conv[j] != 0u);
  return d;
}

// sign-bit pack (bit=1 => negative) via wave ballot; one u64 per 64 floats
__global__ void k_bitify(const float* __restrict__ src, u64* __restrict__ dst){
  long gid = (long)blockIdx.x * 256 + threadIdx.x;
  float v = src[gid];
  u64 m = __ballot(v < 0.0f);
  if ((threadIdx.x & 63) == 0) dst[gid >> 6] = m;
}

// init_est is broadcast over b by construction; bitify row b=0 only + Flags init
__global__ void k_bitify0(const float* __restrict__ init_est, u64* __restrict__ tmp0,
                          Flags* fl){
  long gid = (long)blockIdx.x * 256 + threadIdx.x;   // over F_*D_
  float v = init_est[gid];
  u64 m = __ballot(v < 0.0f);
  if ((threadIdx.x & 63) == 0) tmp0[gid >> 6] = m;
  if (blockIdx.x == 0){
    if (threadIdx.x == 0){ fl->done = 0; fl->k = 0; }
    if (threadIdx.x < ITERS_) fl->conv[threadIdx.x] = 1u;
  }
}

// broadcast tmp0[f][w] to estbits[b][f][w] for all b
__global__ void k_bcast(const u64* __restrict__ tmp0, u64* __restrict__ estbits){
  long gid = (long)blockIdx.x * 256 + threadIdx.x;   // over B_*F_*DW_
  estbits[gid] = tmp0[gid & (F_*DW_ - 1)];
}

// one pass over cb: cbbT[f][w][m] (bit-packed) AND cbT8[f][d][m] (i8 +-1)
__global__ void k_cb_prep(const float* __restrict__ cb, u64* __restrict__ cbbT,
                          i8* __restrict__ cbT8){
  __shared__ i8 tile[64][68];
  int bx = blockIdx.x;
  int f = bx >> 10;
  int r = bx & 1023;
  int mt = r >> 7, dt = r & 127;
  for (int it = 0; it < 16; ++it){
    int lid = threadIdx.x + it*256;
    int i = lid >> 6, j = lid & 63;   // i = m-local (wave-uniform), j = d-local = lane
    float v = cb[((long)(f*M_ + mt*64 + i))*D_ + dt*64 + j];
    tile[j][i] = (v < 0.0f) ? (i8)-1 : (i8)1;
    u64 msk = __ballot(v < 0.0f);     // bit L = sign at d = dt*64 + L
    if (j == 0) cbbT[((long)(f*DW_ + dt))*M_ + mt*64 + i] = msk;
  }
  __syncthreads();
  for (int it = 0; it < 4; ++it){
    int lid = threadIdx.x + it*256;   // 1024 jobs: 64 d x 16 m-groups
    int dd = lid >> 4, mg = lid & 15;
    u32 p = (u32)(unsigned char)tile[dd][mg*4+0]
          | ((u32)(unsigned char)tile[dd][mg*4+1] << 8)
          | ((u32)(unsigned char)tile[dd][mg*4+2] << 16)
          | ((u32)(unsigned char)tile[dd][mg*4+3] << 24);
    *(u32*)(cbT8 + ((long)(f*D_ + dt*64 + dd))*M_ + mt*64 + mg*4) = p;
  }
}

// forward v4: nb = in ^ (xor of other three est); v[m] = 4096 - popc(nb ^ cb[m]).
// Block = 8 b-rows x 512 m (FULL M) for one f; 512 blocks = 128 bt x 4 f;
// 256 threads, TWO m per thread (m, m+256). Theory (R8 post-mortem): forward
// is LDS-pipe-bound on the wave-uniform nbs broadcasts (16 waves/CU x 512
// ds_read_b128 x ~10cyc ~= 35-40us). Processing 2 m per broadcast halves
// per-CU LDS instructions (8 waves x 512); VALU total unchanged (~15us).
// XCD map: id%8 = f + 4*(bt&1) keeps each XCD on its 512KB cbbT f-slice.
__global__ __launch_bounds__(256) void k_forward4(
    const u64* __restrict__ inbits, const u64* __restrict__ estbits,
    const u64* __restrict__ cbbT, i8* __restrict__ Aq, i8* __restrict__ Ar,
    const Flags* __restrict__ fl, int iter){
  if (conv_prefix_done(fl->conv, iter)) return;
  __shared__ u64 nbs[DW_][10];   // [w][bb], pad 10 (16B-aligned bb-pairs)
  int id = blockIdx.x;
  int rr = id & 7;
  int f   = rr & 3;
  int btl = rr >> 2;
  int bth = id >> 3;             // 0..63
  int bt  = bth*2 + btl;         // 0..127
  int b0  = bt * 8;
  int tid = threadIdx.x;
  for (int idx = tid; idx < 8*DW_; idx += 256){
    int w = idx & 127, bb = idx >> 7;
    const u64* eb = estbits + (long)(b0 + bb)*F_*DW_;
    u64 all = eb[w] ^ eb[DW_+w] ^ eb[2*DW_+w] ^ eb[3*DW_+w];
    nbs[w][bb] = inbits[(long)(b0 + bb)*DW_ + w] ^ all ^ eb[f*DW_ + w];
  }
  __syncthreads();
  int m = tid;                   // handles m and m+256
  int acc0[8], acc1[8];
  #pragma unroll
  for (int bb = 0; bb < 8; ++bb){ acc0[bb] = 0; acc1[bb] = 0; }
  const u64* cbf = cbbT + (long)f*DW_*M_ + m;
  #pragma unroll 1
  for (int w0 = 0; w0 < DW_; w0 += 4){
    u64 c0[4], c1[4];
    #pragma unroll
    for (int j = 0; j < 4; ++j){
      c0[j] = cbf[(long)(w0 + j)*M_];
      c1[j] = cbf[(long)(w0 + j)*M_ + 256];
    }
    #pragma unroll
    for (int j = 0; j < 4; ++j){
      int w = w0 + j;
      u64x2 n01 = *(const u64x2*)&nbs[w][0];
      u64x2 n23 = *(const u64x2*)&nbs[w][2];
      u64x2 n45 = *(const u64x2*)&nbs[w][4];
      u64x2 n67 = *(const u64x2*)&nbs[w][6];
      u64 ca = c0[j], cb_ = c1[j];
      acc0[0] += (int)__popcll(n01.x ^ ca);
      acc0[1] += (int)__popcll(n01.y ^ ca);
      acc0[2] += (int)__popcll(n23.x ^ ca);
      acc0[3] += (int)__popcll(n23.y ^ ca);
      acc0[4] += (int)__popcll(n45.x ^ ca);
      acc0[5] += (int)__popcll(n45.y ^ ca);
      acc0[6] += (int)__popcll(n67.x ^ ca);
      acc0[7] += (int)__popcll(n67.y ^ ca);
      acc1[0] += (int)__popcll(n01.x ^ cb_);
      acc1[1] += (int)__popcll(n01.y ^ cb_);
      acc1[2] += (int)__popcll(n23.x ^ cb_);
      acc1[3] += (int)__popcll(n23.y ^ cb_);
      acc1[4] += (int)__popcll(n45.x ^ cb_);
      acc1[5] += (int)__popcll(n45.y ^ cb_);
      acc1[6] += (int)__popcll(n67.x ^ cb_);
      acc1[7] += (int)__popcll(n67.y ^ cb_);
    }
  }
  #pragma unroll
  for (int bb = 0; bb < 8; ++bb){
    long base = ((long)(f*B_ + b0 + bb))*M_;
    int v0 = 4096 - acc0[bb];
    int r0 = ((v0 + 32) & 63) - 32;
    Aq[base + m] = (i8)((v0 - r0) >> 6);
    Ar[base + m] = (i8)r0;
    int v1 = 4096 - acc1[bb];
    int r1 = ((v1 + 32) & 63) - 32;
    Aq[base + m + 256] = (i8)((v1 - r1) >> 6);
    Ar[base + m + 256] = (i8)r1;
  }
}

// backward (VERIFIED R5/R6 version): y[b][d] = sum q*(64c) + sum r*c, exact.
// i8 MFMA 16x16x64, double-buffered DMA, d-tile 256. __syncthreads per kt is
// the correct sync: vmcnt is per-wave, so the cross-wave "DMA complete" fact
// must flow through the barrier's full drain. Depth-2 counted-vmcnt needs a
// 96KB ring -> 1 block/CU (TLP collapse) — lever recorded as exhausted at
// this tile shape (R7 post-mortem).
// f-partitioned XCD grid: id%8 = f*2 + (d-half); 1024 blocks.
__global__ __launch_bounds__(256, 2) void k_backward_d256(
    const i8* __restrict__ Aq, const i8* __restrict__ Ar, const i8* __restrict__ cbT8,
    u64* __restrict__ estbits, Flags* fl, int iter){
  if (conv_prefix_done(fl->conv, iter)) return;
  __shared__ __attribute__((aligned(16))) i8 smem[2*SMSZ2]; // 65536 B
  int id = blockIdx.x;
  int rr = id & 7;
  int f  = rr >> 1;
  int dh = rr & 1;
  int qq = id >> 3;
  int bt = qq & 7;
  int dtl= qq >> 3;           // 0..15
  int dtp= dh*16 + dtl;       // 0..31 (256-wide d tiles)
  int b0 = bt*128, d0 = dtp*256;
  int tid = threadIdx.x;
  int wv = tid >> 6, lane = tid & 63, l16 = lane & 15, quad = lane >> 4;
  int rl = lane >> 2, pl = lane & 3;   // DMA: 4 lanes per 64B row

  i32x4 zero = {0, 0, 0, 0};
  i32x4 acc[2][16];
  #pragma unroll
  for (int i = 0; i < 2; ++i)
    #pragma unroll
    for (int j = 0; j < 16; ++j) acc[i][j] = zero;

  const i8* Aqg = Aq + ((long)f*B_ + b0)*M_;
  const i8* Arg = Ar + ((long)f*B_ + b0)*M_;
  const i8* Bg  = cbT8 + ((long)f*D_ + d0)*M_;

  // per-wave DMA plan: 32 issues = Aq 8 + Ar 8 + B 16 windows(16 rows each);
  // wave takes 8. lane fetches global chunk (pl ^ ((rl>>1)&3)) so LDS slot c'
  // holds chunk c'^swz (matches read-side swizzle).
  const i8* gsrc[8];
  i8* lbase[8];
  int swz = (rl >> 1) & 3;
  #pragma unroll
  for (int j2 = 0; j2 < 8; ++j2){
    int job = j2*4 + wv;            // 0..31
    const i8* src; i8* lb; int jj;
    if (job < 8)      { src = Aqg; jj = job;      lb = smem +         jj*1024; }
    else if (job < 16){ src = Arg; jj = job - 8;  lb = smem +  8192 + jj*1024; }
    else              { src = Bg;  jj = job - 16; lb = smem + 16384 + jj*1024; }
    gsrc[j2]  = src + (long)(jj*16 + rl)*M_ + ((pl ^ swz) << 4);
    lbase[j2] = lb;                 // HW adds lane*16B
  }

  // prologue: issue kt=0 into buffer 0
  #pragma unroll
  for (int j2 = 0; j2 < 8; ++j2)
    gload_lds16(gsrc[j2], lbase[j2]);

  for (int kt = 0; kt < 8; ++kt){
    __syncthreads();   // drains buffer[kt&1]'s DMA; frees buffer[(kt+1)&1] reads
    if (kt < 7){
      int nb = (kt + 1) & 1, k0 = (kt + 1)*64;
      #pragma unroll
      for (int j2 = 0; j2 < 8; ++j2)
        gload_lds16(gsrc[j2] + k0, lbase[j2] + nb*SMSZ2);
    }
    const i8* sb = smem + (kt & 1)*SMSZ2;
    i32x4 aq[2], ar[2];
    #pragma unroll
    for (int rt = 0; rt < 2; ++rt){
      int row = wv*32 + rt*16 + l16;     // A[m=lane&15][k=quad*16+j]
      int c = (quad ^ ((row >> 1) & 3)) << 4;
      aq[rt] = *(const i32x4*)(sb +        row*64 + c);
      ar[rt] = *(const i32x4*)(sb + 8192 + row*64 + c);
    }
    #pragma unroll
    for (int ct = 0; ct < 16; ++ct){
      int rowB = ct*16 + l16;            // B[k=quad*16+j][n=lane&15] via B^T tile
      int c = (quad ^ ((rowB >> 1) & 3)) << 4;
      i32x4 bb = *(const i32x4*)(sb + 16384 + rowB*64 + c);
      i32x4 bb64;
      #pragma unroll
      for (int g = 0; g < 4; ++g)
        bb64[g] = (int)(((u32)bb[g] << 6) & 0xC0C0C0C0u);   // 64*c, exact for c=+-1
      acc[0][ct] = __builtin_amdgcn_mfma_i32_16x16x64_i8(aq[0], bb64, acc[0][ct], 0, 0, 0);
      acc[0][ct] = __builtin_amdgcn_mfma_i32_16x16x64_i8(ar[0], bb,   acc[0][ct], 0, 0, 0);
      acc[1][ct] = __builtin_amdgcn_mfma_i32_16x16x64_i8(aq[1], bb64, acc[1][ct], 0, 0, 0);
      acc[1][ct] = __builtin_amdgcn_mfma_i32_16x16x64_i8(ar[1], bb,   acc[1][ct], 0, 0, 0);
    }
  }

  // ballot epilogue: C/D layout col=lane&15, row=quad*4+reg. ballot bit(16q+t)
  // = sign at (row q*4+r, col ct*16+t). Row covers 256 d-cols = 4 u64 words.
  // Lane<16 holds word pw=lane&3 of row-quad q3=lane>>2. All sign-words
  // computed first, then batched old-estbits reads, one compare/write pass.
  int q3 = (lane >> 2) & 3, pw = lane & 3;
  int pw1 = pw & 1, pw2 = pw >> 1;
  u64 wreg[2][4];
  #pragma unroll
  for (int rt = 0; rt < 2; ++rt){
    #pragma unroll
    for (int r = 0; r < 4; ++r){
      u64 g0[4], g1[4], g2[4], g3[4];
      #pragma unroll
      for (int c = 0; c < 4; ++c){
        g0[c] = __ballot(acc[rt][c][r]      < 0);
        g1[c] = __ballot(acc[rt][4 + c][r]  < 0);
        g2[c] = __ballot(acc[rt][8 + c][r]  < 0);
        g3[c] = __ballot(acc[rt][12 + c][r] < 0);
      }
      u64 word = 0;
      #pragma unroll
      for (int c = 0; c < 4; ++c){
        u64 s = pw2 ? (pw1 ? g3[c] : g2[c]) : (pw1 ? g1[c] : g0[c]);
        word |= ((s >> (16*q3)) & 0xFFFFull) << (16*c);
      }
      wreg[rt][r] = word;
    }
  }
  u64 oldv[2][4];
  if (lane < 16){
    #pragma unroll
    for (int rt = 0; rt < 2; ++rt)
      #pragma unroll
      for (int r = 0; r < 4; ++r){
        int row = wv*32 + rt*16 + q3*4 + r;
        oldv[rt][r] = estbits[((long)(b0 + row)*F_ + f)*DW_ + dtp*4 + pw];
      }
  }
  u32 flag = 0;
  if (lane < 16){
    #pragma unroll
    for (int rt = 0; rt < 2; ++rt)
      #pragma unroll
      for (int r = 0; r < 4; ++r){
        int row = wv*32 + rt*16 + q3*4 + r;
        long addr = ((long)(b0 + row)*F_ + f)*DW_ + dtp*4 + pw;
        estbits[addr] = wreg[rt][r];
        flag |= (oldv[rt][r] != wreg[rt][r]) ? 1u : 0u;
      }
  }
  u32 mymiss = (u32)(__ballot(flag != 0) != 0ull);
  if (lane == 0 && mymiss) atomicAnd(&fl->conv[iter], 0u);
}

// final: outcome = argmax_m |sim|, first-occurrence ties (exact integers).
__global__ __launch_bounds__(256) void k_outcome(
    const u64* __restrict__ estbits, const u64* __restrict__ cbbT,
    const Flags* __restrict__ fl, float* __restrict__ out){
  __shared__ u64 es[8][DW_];
  __shared__ int redv[4][8], redi[4][8];
  int f = blockIdx.y, b0 = blockIdx.x * 8;
  int tid = threadIdx.x, wv = tid >> 6, lane = tid & 63;
  for (int idx = tid; idx < 8*DW_; idx += 256){
    int bb = idx >> 7, w = idx & 127;
    es[bb][w] = estbits[((long)(b0 + bb)*F_ + f)*DW_ + w];
  }
  __syncthreads();
  const u64* cbf = cbbT + (long)f*DW_*M_;
  int m0 = tid, m1 = tid + 256;
  int acc0[8], acc1[8];
  #pragma unroll
  for (int bb = 0; bb < 8; ++bb){ acc0[bb] = 0; acc1[bb] = 0; }
  for (int w = 0; w < DW_; ++w){
    u64 c0 = cbf[(long)w*M_ + m0];
    u64 c1 = cbf[(long)w*M_ + m1];
    #pragma unroll
    for (int bb = 0; bb < 8; ++bb){
      u64 e = es[bb][w];
      acc0[bb] += (int)__popcll(e ^ c0);
      acc1[bb] += (int)__popcll(e ^ c1);
    }
  }
  int bv[8], bi[8];
  #pragma unroll
  for (int bb = 0; bb < 8; ++bb){
    int a0 = 4096 - acc0[bb]; if (a0 < 0) a0 = -a0;
    int a1 = 4096 - acc1[bb]; if (a1 < 0) a1 = -a1;
    bv[bb] = a0; bi[bb] = m0;
    if (a1 > a0){ bv[bb] = a1; bi[bb] = m1; }   // tie keeps lower m
  }
  for (int off = 32; off; off >>= 1){
    #pragma unroll
    for (int bb = 0; bb < 8; ++bb){
      int ov = __shfl_xor(bv[bb], off, 64);
      int oi = __shfl_xor(bi[bb], off, 64);
      if (ov > bv[bb] || (ov == bv[bb] && oi < bi[bb])){ bv[bb] = ov; bi[bb] = oi; }
    }
  }
  if (lane == 0)
    #pragma unroll
    for (int bb = 0; bb < 8; ++bb){ redv[wv][bb] = bv[bb]; redi[wv][bb] = bi[bb]; }
  __syncthreads();
  if (tid < 8){
    int v0 = redv[0][tid], i0 = redi[0][tid];
    for (int w = 1; w < 4; ++w){
      int v = redv[w][tid], i = redi[w][tid];
      if (v > v0 || (v == v0 && i < i0)){ v0 = v; i0 = i; }
    }
    out[(long)(b0 + tid)*F_ + f] = (float)i0;
  }
  if (blockIdx.x == 0 && f == 0 && tid == 0){
    int k = ITERS_;
    for (int j = 0; j < ITERS_; ++j) if (fl->conv[j]){ k = j + 1; break; }
    out[B_*F_] = (float)k;
  }
}

__global__ void k_unpack(const u64* __restrict__ estbits, float* __restrict__ out){
  long gid = (long)blockIdx.x*256 + threadIdx.x;   // over B*F*D/4
  int bf = (int)(gid >> 11);
  int d4 = (int)(gid & 2047);
  u64 word = estbits[(long)bf*DW_ + (d4 >> 4)];
  u32 nib = (u32)(word >> ((d4 & 15) * 4)) & 0xFu;
  long base = (long)(B_*F_ + 1) + (long)bf*D_ + (long)d4*4;
  out[base+0] = (nib & 1u) ? -1.0f : 1.0f;
  out[base+1] = (nib & 2u) ? -1.0f : 1.0f;
  out[base+2] = (nib & 4u) ? -1.0f : 1.0f;
  out[base+3] = (nib & 8u) ? -1.0f : 1.0f;
}

extern "C" void kernel_launch(void* const* d_in, const int* in_sizes, int n_in,
                              void* d_out, int out_size, void* d_ws, size_t ws_size,
                              hipStream_t stream){
  const float* input    = (const float*)d_in[0];
  const float* init_est = (const float*)d_in[1];
  const float* cb       = (const float*)d_in[2];
  char* ws   = (char*)d_ws;
  char* outc = (char*)d_out;

  size_t off = 0;
  Flags* fl = (Flags*)(ws); off = 1024;
  u64* tmp0    = (u64*)(ws + off); off += (size_t)F_*DW_*8;        // 4 KB
  off = (off + 1023) & ~size_t(1023);
  u64* inbits  = (u64*)(ws + off); off += (size_t)B_*DW_*8;        // 1 MB
  u64* estbits = (u64*)(ws + off); off += (size_t)B_*F_*DW_*8;     // 4 MB
  u64* cbbT    = (u64*)(ws + off); off += (size_t)F_*DW_*M_*8;     // 2 MB
  size_t big = (size_t)F_*D_*M_ + 2*(size_t)F_*B_*M_;              // 16 MB + 4 MB
  i8 *cbT8, *Aq, *Ar;
  if (ws_size >= off + big + 1024){
    cbT8 = (i8*)(ws + off); off += (size_t)F_*D_*M_;
    Aq   = (i8*)(ws + off); off += (size_t)F_*B_*M_;
    Ar   = (i8*)(ws + off); off += (size_t)F_*B_*M_;
  } else {
    // d_out is 33558529 float32 = 128.02 MiB; est chunk spans [16388, 134234116).
    // Park scratch high — only the final k_unpack overwrites it, after last use.
    cbT8 = (i8*)(outc + (80ull << 20));    // 80..96 MiB
    Aq   = (i8*)(outc + (100ull << 20));   // 100..102 MiB
    Ar   = (i8*)(outc + (104ull << 20));   // 104..106 MiB
  }

  k_bitify0<<<(F_*D_)/256, 256, 0, stream>>>(init_est, tmp0, fl);
  k_bcast<<<(B_*F_*DW_)/256, 256, 0, stream>>>(tmp0, estbits);
  k_bitify<<<(B_*(long)D_)/256, 256, 0, stream>>>(input, inbits);
  k_cb_prep<<<4096, 256, 0, stream>>>(cb, cbbT, cbT8);

  for (int it = 0; it < ITERS_; ++it){
    k_forward4<<<512, 256, 0, stream>>>(inbits, estbits, cbbT, Aq, Ar, fl, it);
    k_backward_d256<<<1024, 256, 0, stream>>>(Aq, Ar, cbT8, estbits, fl, it);
  }

  k_outcome<<<dim3(B_/8, F_), 256, 0, stream>>>(estbits, cbbT, fl, (float*)d_out);
  k_unpack<<<((long)B_*F_*D_/4)/256, 256, 0, stream>>>(estbits, (float*)d_out);
}

// Round 10
// 1437.820 us; speedup vs baseline: 1.0188x; 1.0188x over previous
//
#include <hip/hip_runtime.h>
#include <stdint.h>

#define B_ 1024
#define F_ 4
#define M_ 512
#define D_ 8192
#define ITERS_ 10
#define DW_ 128      // D/64 u64 words per D-vector
#define SMSZ2 32768  // one staging buffer: Aq 8K + Ar 8K + B 16K

typedef unsigned long long u64;
typedef unsigned int u32;
typedef unsigned short u16;
typedef signed char i8;

typedef int i32x4 __attribute__((ext_vector_type(4)));
typedef u64 u64x2 __attribute__((ext_vector_type(2)));

struct Flags { u32 done; u32 k; u32 conv[ITERS_]; };

__device__ inline void gload_lds16(const void* g, void* l){
  __builtin_amdgcn_global_load_lds(
      (const __attribute__((address_space(1))) void*)g,
      (__attribute__((address_space(3))) void*)l, 16, 0, 0);
}

__device__ inline bool conv_prefix_done(const u32* conv, int iter){
  bool d = false;
  for (int j = 0; j < iter; ++j) d |= (conv[j] != 0u);
  return d;
}

// sign-bit pack (bit=1 => negative) via wave ballot; one u64 per 64 floats
__global__ void k_bitify(const float* __restrict__ src, u64* __restrict__ dst){
  long gid = (long)blockIdx.x * 256 + threadIdx.x;
  float v = src[gid];
  u64 m = __ballot(v < 0.0f);
  if ((threadIdx.x & 63) == 0) dst[gid >> 6] = m;
}

// init_est is broadcast over b by construction; bitify row b=0 only + Flags init
__global__ void k_bitify0(const float* __restrict__ init_est, u64* __restrict__ tmp0,
                          Flags* fl){
  long gid = (long)blockIdx.x * 256 + threadIdx.x;   // over F_*D_
  float v = init_est[gid];
  u64 m = __ballot(v < 0.0f);
  if ((threadIdx.x & 63) == 0) tmp0[gid >> 6] = m;
  if (blockIdx.x == 0){
    if (threadIdx.x == 0){ fl->done = 0; fl->k = 0; }
    if (threadIdx.x < ITERS_) fl->conv[threadIdx.x] = 1u;
  }
}

// broadcast tmp0[f][w] to estbits[b][f][w] for all b
__global__ void k_bcast(const u64* __restrict__ tmp0, u64* __restrict__ estbits){
  long gid = (long)blockIdx.x * 256 + threadIdx.x;   // over B_*F_*DW_
  estbits[gid] = tmp0[gid & (F_*DW_ - 1)];
}

// one pass over cb: cbbT[f][w][m] (bit-packed) AND cbT8[f][d][m] (i8 +-1)
__global__ void k_cb_prep(const float* __restrict__ cb, u64* __restrict__ cbbT,
                          i8* __restrict__ cbT8){
  __shared__ i8 tile[64][68];
  int bx = blockIdx.x;
  int f = bx >> 10;
  int r = bx & 1023;
  int mt = r >> 7, dt = r & 127;
  for (int it = 0; it < 16; ++it){
    int lid = threadIdx.x + it*256;
    int i = lid >> 6, j = lid & 63;   // i = m-local (wave-uniform), j = d-local = lane
    float v = cb[((long)(f*M_ + mt*64 + i))*D_ + dt*64 + j];
    tile[j][i] = (v < 0.0f) ? (i8)-1 : (i8)1;
    u64 msk = __ballot(v < 0.0f);     // bit L = sign at d = dt*64 + L
    if (j == 0) cbbT[((long)(f*DW_ + dt))*M_ + mt*64 + i] = msk;
  }
  __syncthreads();
  for (int it = 0; it < 4; ++it){
    int lid = threadIdx.x + it*256;   // 1024 jobs: 64 d x 16 m-groups
    int dd = lid >> 4, mg = lid & 15;
    u32 p = (u32)(unsigned char)tile[dd][mg*4+0]
          | ((u32)(unsigned char)tile[dd][mg*4+1] << 8)
          | ((u32)(unsigned char)tile[dd][mg*4+2] << 16)
          | ((u32)(unsigned char)tile[dd][mg*4+3] << 24);
    *(u32*)(cbT8 + ((long)(f*D_ + dt*64 + dd))*M_ + mt*64 + mg*4) = p;
  }
}

// forward v5: v2's verified inner loop (transposed nbs [w][bb] pad 10, 4x
// ds_read_b128/iter, f-pure XCD map) at DOUBLE the wave parallelism:
// 128-thread blocks, 2048 blocks (8 b x 128 m each; 4 f x 4 mq x 128 bt).
// Theory (R9): forward is latency-bound with poor per-wave ILP — halving
// waves/CU cost +6us/dispatch, so doubling (16 -> ~30 waves/CU; LDS
// 10.2KB/block caps at 15 blocks/CU) should recover more hiding. Cost:
// nbs staging traffic 32->64 MB (L2-resident est), ~2us/iter.
__global__ __launch_bounds__(128) void k_forward5(
    const u64* __restrict__ inbits, const u64* __restrict__ estbits,
    const u64* __restrict__ cbbT, i8* __restrict__ Aq, i8* __restrict__ Ar,
    const Flags* __restrict__ fl, int iter){
  if (conv_prefix_done(fl->conv, iter)) return;
  __shared__ u64 nbs[DW_][10];   // [w][bb], pad 10 (16B-aligned bb-pairs)
  int id = blockIdx.x;
  int rr = id & 7;
  int f   = rr & 3;
  int btl = rr >> 2;
  int q   = id >> 3;             // 0..255
  int mq  = q & 3;               // m-quarter 0..3
  int bth = q >> 2;              // 0..63
  int bt  = bth*2 + btl;         // 0..127
  int b0  = bt * 8;
  int tid = threadIdx.x;
  for (int idx = tid; idx < 8*DW_; idx += 128){
    int w = idx & 127, bb = idx >> 7;
    const u64* eb = estbits + (long)(b0 + bb)*F_*DW_;
    u64 all = eb[w] ^ eb[DW_+w] ^ eb[2*DW_+w] ^ eb[3*DW_+w];
    nbs[w][bb] = inbits[(long)(b0 + bb)*DW_ + w] ^ all ^ eb[f*DW_ + w];
  }
  __syncthreads();
  int m = mq*128 + tid;
  int acc[8];
  #pragma unroll
  for (int bb = 0; bb < 8; ++bb) acc[bb] = 0;
  const u64* cbf = cbbT + (long)f*DW_*M_ + m;
  #pragma unroll 2
  for (int w = 0; w < DW_; ++w){
    u64 c = cbf[(long)w*M_];
    u64x2 n01 = *(const u64x2*)&nbs[w][0];
    u64x2 n23 = *(const u64x2*)&nbs[w][2];
    u64x2 n45 = *(const u64x2*)&nbs[w][4];
    u64x2 n67 = *(const u64x2*)&nbs[w][6];
    acc[0] += (int)__popcll(n01.x ^ c);
    acc[1] += (int)__popcll(n01.y ^ c);
    acc[2] += (int)__popcll(n23.x ^ c);
    acc[3] += (int)__popcll(n23.y ^ c);
    acc[4] += (int)__popcll(n45.x ^ c);
    acc[5] += (int)__popcll(n45.y ^ c);
    acc[6] += (int)__popcll(n67.x ^ c);
    acc[7] += (int)__popcll(n67.y ^ c);
  }
  #pragma unroll
  for (int bb = 0; bb < 8; ++bb){
    int v = 4096 - acc[bb];
    int r = ((v + 32) & 63) - 32;
    int qd = (v - r) >> 6;
    long base = ((long)(f*B_ + b0 + bb))*M_ + m;
    Aq[base] = (i8)qd;
    Ar[base] = (i8)r;
  }
}

// backward (VERIFIED R5/R6 version): y[b][d] = sum q*(64c) + sum r*c, exact.
// i8 MFMA 16x16x64, double-buffered DMA, d-tile 256. __syncthreads per kt is
// the correct sync: vmcnt is per-wave, so the cross-wave "DMA complete" fact
// must flow through the barrier's full drain. Depth-2 counted-vmcnt needs a
// 96KB ring -> 1 block/CU (TLP collapse) — lever recorded as exhausted at
// this tile shape (R7 post-mortem).
// f-partitioned XCD grid: id%8 = f*2 + (d-half); 1024 blocks.
__global__ __launch_bounds__(256, 2) void k_backward_d256(
    const i8* __restrict__ Aq, const i8* __restrict__ Ar, const i8* __restrict__ cbT8,
    u64* __restrict__ estbits, Flags* fl, int iter){
  if (conv_prefix_done(fl->conv, iter)) return;
  __shared__ __attribute__((aligned(16))) i8 smem[2*SMSZ2]; // 65536 B
  int id = blockIdx.x;
  int rr = id & 7;
  int f  = rr >> 1;
  int dh = rr & 1;
  int qq = id >> 3;
  int bt = qq & 7;
  int dtl= qq >> 3;           // 0..15
  int dtp= dh*16 + dtl;       // 0..31 (256-wide d tiles)
  int b0 = bt*128, d0 = dtp*256;
  int tid = threadIdx.x;
  int wv = tid >> 6, lane = tid & 63, l16 = lane & 15, quad = lane >> 4;
  int rl = lane >> 2, pl = lane & 3;   // DMA: 4 lanes per 64B row

  i32x4 zero = {0, 0, 0, 0};
  i32x4 acc[2][16];
  #pragma unroll
  for (int i = 0; i < 2; ++i)
    #pragma unroll
    for (int j = 0; j < 16; ++j) acc[i][j] = zero;

  const i8* Aqg = Aq + ((long)f*B_ + b0)*M_;
  const i8* Arg = Ar + ((long)f*B_ + b0)*M_;
  const i8* Bg  = cbT8 + ((long)f*D_ + d0)*M_;

  // per-wave DMA plan: 32 issues = Aq 8 + Ar 8 + B 16 windows(16 rows each);
  // wave takes 8. lane fetches global chunk (pl ^ ((rl>>1)&3)) so LDS slot c'
  // holds chunk c'^swz (matches read-side swizzle).
  const i8* gsrc[8];
  i8* lbase[8];
  int swz = (rl >> 1) & 3;
  #pragma unroll
  for (int j2 = 0; j2 < 8; ++j2){
    int job = j2*4 + wv;            // 0..31
    const i8* src; i8* lb; int jj;
    if (job < 8)      { src = Aqg; jj = job;      lb = smem +         jj*1024; }
    else if (job < 16){ src = Arg; jj = job - 8;  lb = smem +  8192 + jj*1024; }
    else              { src = Bg;  jj = job - 16; lb = smem + 16384 + jj*1024; }
    gsrc[j2]  = src + (long)(jj*16 + rl)*M_ + ((pl ^ swz) << 4);
    lbase[j2] = lb;                 // HW adds lane*16B
  }

  // prologue: issue kt=0 into buffer 0
  #pragma unroll
  for (int j2 = 0; j2 < 8; ++j2)
    gload_lds16(gsrc[j2], lbase[j2]);

  for (int kt = 0; kt < 8; ++kt){
    __syncthreads();   // drains buffer[kt&1]'s DMA; frees buffer[(kt+1)&1] reads
    if (kt < 7){
      int nb = (kt + 1) & 1, k0 = (kt + 1)*64;
      #pragma unroll
      for (int j2 = 0; j2 < 8; ++j2)
        gload_lds16(gsrc[j2] + k0, lbase[j2] + nb*SMSZ2);
    }
    const i8* sb = smem + (kt & 1)*SMSZ2;
    i32x4 aq[2], ar[2];
    #pragma unroll
    for (int rt = 0; rt < 2; ++rt){
      int row = wv*32 + rt*16 + l16;     // A[m=lane&15][k=quad*16+j]
      int c = (quad ^ ((row >> 1) & 3)) << 4;
      aq[rt] = *(const i32x4*)(sb +        row*64 + c);
      ar[rt] = *(const i32x4*)(sb + 8192 + row*64 + c);
    }
    #pragma unroll
    for (int ct = 0; ct < 16; ++ct){
      int rowB = ct*16 + l16;            // B[k=quad*16+j][n=lane&15] via B^T tile
      int c = (quad ^ ((rowB >> 1) & 3)) << 4;
      i32x4 bb = *(const i32x4*)(sb + 16384 + rowB*64 + c);
      i32x4 bb64;
      #pragma unroll
      for (int g = 0; g < 4; ++g)
        bb64[g] = (int)(((u32)bb[g] << 6) & 0xC0C0C0C0u);   // 64*c, exact for c=+-1
      acc[0][ct] = __builtin_amdgcn_mfma_i32_16x16x64_i8(aq[0], bb64, acc[0][ct], 0, 0, 0);
      acc[0][ct] = __builtin_amdgcn_mfma_i32_16x16x64_i8(ar[0], bb,   acc[0][ct], 0, 0, 0);
      acc[1][ct] = __builtin_amdgcn_mfma_i32_16x16x64_i8(aq[1], bb64, acc[1][ct], 0, 0, 0);
      acc[1][ct] = __builtin_amdgcn_mfma_i32_16x16x64_i8(ar[1], bb,   acc[1][ct], 0, 0, 0);
    }
  }

  // ballot epilogue: C/D layout col=lane&15, row=quad*4+reg. ballot bit(16q+t)
  // = sign at (row q*4+r, col ct*16+t). Row covers 256 d-cols = 4 u64 words.
  // Lane<16 holds word pw=lane&3 of row-quad q3=lane>>2. All sign-words
  // computed first, then batched old-estbits reads, one compare/write pass.
  int q3 = (lane >> 2) & 3, pw = lane & 3;
  int pw1 = pw & 1, pw2 = pw >> 1;
  u64 wreg[2][4];
  #pragma unroll
  for (int rt = 0; rt < 2; ++rt){
    #pragma unroll
    for (int r = 0; r < 4; ++r){
      u64 g0[4], g1[4], g2[4], g3[4];
      #pragma unroll
      for (int c = 0; c < 4; ++c){
        g0[c] = __ballot(acc[rt][c][r]      < 0);
        g1[c] = __ballot(acc[rt][4 + c][r]  < 0);
        g2[c] = __ballot(acc[rt][8 + c][r]  < 0);
        g3[c] = __ballot(acc[rt][12 + c][r] < 0);
      }
      u64 word = 0;
      #pragma unroll
      for (int c = 0; c < 4; ++c){
        u64 s = pw2 ? (pw1 ? g3[c] : g2[c]) : (pw1 ? g1[c] : g0[c]);
        word |= ((s >> (16*q3)) & 0xFFFFull) << (16*c);
      }
      wreg[rt][r] = word;
    }
  }
  u64 oldv[2][4];
  if (lane < 16){
    #pragma unroll
    for (int rt = 0; rt < 2; ++rt)
      #pragma unroll
      for (int r = 0; r < 4; ++r){
        int row = wv*32 + rt*16 + q3*4 + r;
        oldv[rt][r] = estbits[((long)(b0 + row)*F_ + f)*DW_ + dtp*4 + pw];
      }
  }
  u32 flag = 0;
  if (lane < 16){
    #pragma unroll
    for (int rt = 0; rt < 2; ++rt)
      #pragma unroll
      for (int r = 0; r < 4; ++r){
        int row = wv*32 + rt*16 + q3*4 + r;
        long addr = ((long)(b0 + row)*F_ + f)*DW_ + dtp*4 + pw;
        estbits[addr] = wreg[rt][r];
        flag |= (oldv[rt][r] != wreg[rt][r]) ? 1u : 0u;
      }
  }
  u32 mymiss = (u32)(__ballot(flag != 0) != 0ull);
  if (lane == 0 && mymiss) atomicAnd(&fl->conv[iter], 0u);
}

// final: outcome = argmax_m |sim|, first-occurrence ties (exact integers).
__global__ __launch_bounds__(256) void k_outcome(
    const u64* __restrict__ estbits, const u64* __restrict__ cbbT,
    const Flags* __restrict__ fl, float* __restrict__ out){
  __shared__ u64 es[8][DW_];
  __shared__ int redv[4][8], redi[4][8];
  int f = blockIdx.y, b0 = blockIdx.x * 8;
  int tid = threadIdx.x, wv = tid >> 6, lane = tid & 63;
  for (int idx = tid; idx < 8*DW_; idx += 256){
    int bb = idx >> 7, w = idx & 127;
    es[bb][w] = estbits[((long)(b0 + bb)*F_ + f)*DW_ + w];
  }
  __syncthreads();
  const u64* cbf = cbbT + (long)f*DW_*M_;
  int m0 = tid, m1 = tid + 256;
  int acc0[8], acc1[8];
  #pragma unroll
  for (int bb = 0; bb < 8; ++bb){ acc0[bb] = 0; acc1[bb] = 0; }
  for (int w = 0; w < DW_; ++w){
    u64 c0 = cbf[(long)w*M_ + m0];
    u64 c1 = cbf[(long)w*M_ + m1];
    #pragma unroll
    for (int bb = 0; bb < 8; ++bb){
      u64 e = es[bb][w];
      acc0[bb] += (int)__popcll(e ^ c0);
      acc1[bb] += (int)__popcll(e ^ c1);
    }
  }
  int bv[8], bi[8];
  #pragma unroll
  for (int bb = 0; bb < 8; ++bb){
    int a0 = 4096 - acc0[bb]; if (a0 < 0) a0 = -a0;
    int a1 = 4096 - acc1[bb]; if (a1 < 0) a1 = -a1;
    bv[bb] = a0; bi[bb] = m0;
    if (a1 > a0){ bv[bb] = a1; bi[bb] = m1; }   // tie keeps lower m
  }
  for (int off = 32; off; off >>= 1){
    #pragma unroll
    for (int bb = 0; bb < 8; ++bb){
      int ov = __shfl_xor(bv[bb], off, 64);
      int oi = __shfl_xor(bi[bb], off, 64);
      if (ov > bv[bb] || (ov == bv[bb] && oi < bi[bb])){ bv[bb] = ov; bi[bb] = oi; }
    }
  }
  if (lane == 0)
    #pragma unroll
    for (int bb = 0; bb < 8; ++bb){ redv[wv][bb] = bv[bb]; redi[wv][bb] = bi[bb]; }
  __syncthreads();
  if (tid < 8){
    int v0 = redv[0][tid], i0 = redi[0][tid];
    for (int w = 1; w < 4; ++w){
      int v = redv[w][tid], i = redi[w][tid];
      if (v > v0 || (v == v0 && i < i0)){ v0 = v; i0 = i; }
    }
    out[(long)(b0 + tid)*F_ + f] = (float)i0;
  }
  if (blockIdx.x == 0 && f == 0 && tid == 0){
    int k = ITERS_;
    for (int j = 0; j < ITERS_; ++j) if (fl->conv[j]){ k = j + 1; break; }
    out[B_*F_] = (float)k;
  }
}

__global__ void k_unpack(const u64* __restrict__ estbits, float* __restrict__ out){
  long gid = (long)blockIdx.x*256 + threadIdx.x;   // over B*F*D/4
  int bf = (int)(gid >> 11);
  int d4 = (int)(gid & 2047);
  u64 word = estbits[(long)bf*DW_ + (d4 >> 4)];
  u32 nib = (u32)(word >> ((d4 & 15) * 4)) & 0xFu;
  long base = (long)(B_*F_ + 1) + (long)bf*D_ + (long)d4*4;
  out[base+0] = (nib & 1u) ? -1.0f : 1.0f;
  out[base+1] = (nib & 2u) ? -1.0f : 1.0f;
  out[base+2] = (nib & 4u) ? -1.0f : 1.0f;
  out[base+3] = (nib & 8u) ? -1.0f : 1.0f;
}

extern "C" void kernel_launch(void* const* d_in, const int* in_sizes, int n_in,
                              void* d_out, int out_size, void* d_ws, size_t ws_size,
                              hipStream_t stream){
  const float* input    = (const float*)d_in[0];
  const float* init_est = (const float*)d_in[1];
  const float* cb       = (const float*)d_in[2];
  char* ws   = (char*)d_ws;
  char* outc = (char*)d_out;

  size_t off = 0;
  Flags* fl = (Flags*)(ws); off = 1024;
  u64* tmp0    = (u64*)(ws + off); off += (size_t)F_*DW_*8;        // 4 KB
  off = (off + 1023) & ~size_t(1023);
  u64* inbits  = (u64*)(ws + off); off += (size_t)B_*DW_*8;        // 1 MB
  u64* estbits = (u64*)(ws + off); off += (size_t)B_*F_*DW_*8;     // 4 MB
  u64* cbbT    = (u64*)(ws + off); off += (size_t)F_*DW_*M_*8;     // 2 MB
  size_t big = (size_t)F_*D_*M_ + 2*(size_t)F_*B_*M_;              // 16 MB + 4 MB
  i8 *cbT8, *Aq, *Ar;
  if (ws_size >= off + big + 1024){
    cbT8 = (i8*)(ws + off); off += (size_t)F_*D_*M_;
    Aq   = (i8*)(ws + off); off += (size_t)F_*B_*M_;
    Ar   = (i8*)(ws + off); off += (size_t)F_*B_*M_;
  } else {
    // d_out is 33558529 float32 = 128.02 MiB; est chunk spans [16388, 134234116).
    // Park scratch high — only the final k_unpack overwrites it, after last use.
    cbT8 = (i8*)(outc + (80ull << 20));    // 80..96 MiB
    Aq   = (i8*)(outc + (100ull << 20));   // 100..102 MiB
    Ar   = (i8*)(outc + (104ull << 20));   // 104..106 MiB
  }

  k_bitify0<<<(F_*D_)/256, 256, 0, stream>>>(init_est, tmp0, fl);
  k_bcast<<<(B_*F_*DW_)/256, 256, 0, stream>>>(tmp0, estbits);
  k_bitify<<<(B_*(long)D_)/256, 256, 0, stream>>>(input, inbits);
  k_cb_prep<<<4096, 256, 0, stream>>>(cb, cbbT, cbT8);

  for (int it = 0; it < ITERS_; ++it){
    k_forward5<<<2048, 128, 0, stream>>>(inbits, estbits, cbbT, Aq, Ar, fl, it);
    k_backward_d256<<<1024, 256, 0, stream>>>(Aq, Ar, cbT8, estbits, fl, it);
  }

  k_outcome<<<dim3(B_/8, F_), 256, 0, stream>>>(estbits, cbbT, fl, (float*)d_out);
  k_unpack<<<((long)B_*F_*D_/4)/256, 256, 0, stream>>>(estbits, (float*)d_out);
}

// Round 11
// 1404.075 us; speedup vs baseline: 1.0433x; 1.0240x over previous
//
#include <hip/hip_runtime.h>
#include <stdint.h>

#define B_ 1024
#define F_ 4
#define M_ 512
#define D_ 8192
#define ITERS_ 10
#define DW_ 128      // D/64 u64 words per D-vector
#define SMSZ2 32768  // one staging buffer: Aq 8K + Ar 8K + B 16K

typedef unsigned long long u64;
typedef unsigned int u32;
typedef unsigned short u16;
typedef signed char i8;

typedef int i32x4 __attribute__((ext_vector_type(4)));
typedef u64 u64x2 __attribute__((ext_vector_type(2)));

struct Flags { u32 done; u32 k; u32 conv[ITERS_]; };

__device__ inline void gload_lds16(const void* g, void* l){
  __builtin_amdgcn_global_load_lds(
      (const __attribute__((address_space(1))) void*)g,
      (__attribute__((address_space(3))) void*)l, 16, 0, 0);
}

__device__ inline bool conv_prefix_done(const u32* conv, int iter){
  bool d = false;
  for (int j = 0; j < iter; ++j) d |= (conv[j] != 0u);
  return d;
}

// sign-bit pack (bit=1 => negative) via wave ballot; one u64 per 64 floats
__global__ void k_bitify(const float* __restrict__ src, u64* __restrict__ dst){
  long gid = (long)blockIdx.x * 256 + threadIdx.x;
  float v = src[gid];
  u64 m = __ballot(v < 0.0f);
  if ((threadIdx.x & 63) == 0) dst[gid >> 6] = m;
}

// init_est is broadcast over b by construction; bitify row b=0 only + Flags init
__global__ void k_bitify0(const float* __restrict__ init_est, u64* __restrict__ tmp0,
                          Flags* fl){
  long gid = (long)blockIdx.x * 256 + threadIdx.x;   // over F_*D_
  float v = init_est[gid];
  u64 m = __ballot(v < 0.0f);
  if ((threadIdx.x & 63) == 0) tmp0[gid >> 6] = m;
  if (blockIdx.x == 0){
    if (threadIdx.x == 0){ fl->done = 0; fl->k = 0; }
    if (threadIdx.x < ITERS_) fl->conv[threadIdx.x] = 1u;
  }
}

// broadcast tmp0[f][w] to estbits[b][f][w] for all b
__global__ void k_bcast(const u64* __restrict__ tmp0, u64* __restrict__ estbits){
  long gid = (long)blockIdx.x * 256 + threadIdx.x;   // over B_*F_*DW_
  estbits[gid] = tmp0[gid & (F_*DW_ - 1)];
}

// one pass over cb: cbbT[f][w][m] (bit-packed) AND cbT8[f][d][m] (i8 +-1)
__global__ void k_cb_prep(const float* __restrict__ cb, u64* __restrict__ cbbT,
                          i8* __restrict__ cbT8){
  __shared__ i8 tile[64][68];
  int bx = blockIdx.x;
  int f = bx >> 10;
  int r = bx & 1023;
  int mt = r >> 7, dt = r & 127;
  for (int it = 0; it < 16; ++it){
    int lid = threadIdx.x + it*256;
    int i = lid >> 6, j = lid & 63;   // i = m-local (wave-uniform), j = d-local = lane
    float v = cb[((long)(f*M_ + mt*64 + i))*D_ + dt*64 + j];
    tile[j][i] = (v < 0.0f) ? (i8)-1 : (i8)1;
    u64 msk = __ballot(v < 0.0f);     // bit L = sign at d = dt*64 + L
    if (j == 0) cbbT[((long)(f*DW_ + dt))*M_ + mt*64 + i] = msk;
  }
  __syncthreads();
  for (int it = 0; it < 4; ++it){
    int lid = threadIdx.x + it*256;   // 1024 jobs: 64 d x 16 m-groups
    int dd = lid >> 4, mg = lid & 15;
    u32 p = (u32)(unsigned char)tile[dd][mg*4+0]
          | ((u32)(unsigned char)tile[dd][mg*4+1] << 8)
          | ((u32)(unsigned char)tile[dd][mg*4+2] << 16)
          | ((u32)(unsigned char)tile[dd][mg*4+3] << 24);
    *(u32*)(cbT8 + ((long)(f*D_ + dt*64 + dd))*M_ + mt*64 + mg*4) = p;
  }
}

// forward v2 (BEST measured config, R6 = 1395us): nb = in ^ (xor of other
// three est); v[m] = 4096 - popc(nb ^ cb[m]). Block = 8 b-rows x 256 m for
// one f (1024 blocks = 128 bt x 4 f x 2 mh; 16 waves/CU). Occupancy curve
// measured R8-R10: 8 waves 1465, 16 waves 1395, 30 waves 1438 -> v2 is the
// optimum; prefetch-depth and LDS-request probes were null. At structural
// floor for this decomposition.
__global__ __launch_bounds__(256) void k_forward2(
    const u64* __restrict__ inbits, const u64* __restrict__ estbits,
    const u64* __restrict__ cbbT, i8* __restrict__ Aq, i8* __restrict__ Ar,
    const Flags* __restrict__ fl, int iter){
  if (conv_prefix_done(fl->conv, iter)) return;
  __shared__ u64 nbs[DW_][10];   // [w][bb], pad 10 (16B-aligned bb-pairs)
  int id = blockIdx.x;
  int rr = id & 7;
  int f   = rr & 3;
  int btl = rr >> 2;
  int q   = id >> 3;
  int bth = q & 63;
  int mh  = q >> 6;              // 0..1
  int bt  = bth*2 + btl;         // 0..127
  int b0  = bt * 8;
  int tid = threadIdx.x;
  for (int idx = tid; idx < 8*DW_; idx += 256){
    int w = idx & 127, bb = idx >> 7;
    const u64* eb = estbits + (long)(b0 + bb)*F_*DW_;
    u64 all = eb[w] ^ eb[DW_+w] ^ eb[2*DW_+w] ^ eb[3*DW_+w];
    nbs[w][bb] = inbits[(long)(b0 + bb)*DW_ + w] ^ all ^ eb[f*DW_ + w];
  }
  __syncthreads();
  int m = mh*256 + tid;
  int acc[8];
  #pragma unroll
  for (int bb = 0; bb < 8; ++bb) acc[bb] = 0;
  const u64* cbf = cbbT + (long)f*DW_*M_ + m;
  #pragma unroll 2
  for (int w = 0; w < DW_; ++w){
    u64 c = cbf[(long)w*M_];
    u64x2 n01 = *(const u64x2*)&nbs[w][0];
    u64x2 n23 = *(const u64x2*)&nbs[w][2];
    u64x2 n45 = *(const u64x2*)&nbs[w][4];
    u64x2 n67 = *(const u64x2*)&nbs[w][6];
    acc[0] += (int)__popcll(n01.x ^ c);
    acc[1] += (int)__popcll(n01.y ^ c);
    acc[2] += (int)__popcll(n23.x ^ c);
    acc[3] += (int)__popcll(n23.y ^ c);
    acc[4] += (int)__popcll(n45.x ^ c);
    acc[5] += (int)__popcll(n45.y ^ c);
    acc[6] += (int)__popcll(n67.x ^ c);
    acc[7] += (int)__popcll(n67.y ^ c);
  }
  #pragma unroll
  for (int bb = 0; bb < 8; ++bb){
    int v = 4096 - acc[bb];
    int r = ((v + 32) & 63) - 32;
    int qd = (v - r) >> 6;
    long base = ((long)(f*B_ + b0 + bb))*M_ + m;
    Aq[base] = (i8)qd;
    Ar[base] = (i8)r;
  }
}

// backward (verified R5/R6 structure) + T5 s_setprio around the MFMA cluster.
// Mechanism: 2 independent blocks/CU at unsynchronized phases -> wave role
// diversity (one block MFMAs while the other stages/drains); setprio biases
// the CU scheduler toward the MFMA-phase waves (the technique's verified
// paying regime; null only on lockstep structures).
// f-partitioned XCD grid: id%8 = f*2 + (d-half); 1024 blocks.
__global__ __launch_bounds__(256, 2) void k_backward_d256(
    const i8* __restrict__ Aq, const i8* __restrict__ Ar, const i8* __restrict__ cbT8,
    u64* __restrict__ estbits, Flags* fl, int iter){
  if (conv_prefix_done(fl->conv, iter)) return;
  __shared__ __attribute__((aligned(16))) i8 smem[2*SMSZ2]; // 65536 B
  int id = blockIdx.x;
  int rr = id & 7;
  int f  = rr >> 1;
  int dh = rr & 1;
  int qq = id >> 3;
  int bt = qq & 7;
  int dtl= qq >> 3;           // 0..15
  int dtp= dh*16 + dtl;       // 0..31 (256-wide d tiles)
  int b0 = bt*128, d0 = dtp*256;
  int tid = threadIdx.x;
  int wv = tid >> 6, lane = tid & 63, l16 = lane & 15, quad = lane >> 4;
  int rl = lane >> 2, pl = lane & 3;   // DMA: 4 lanes per 64B row

  i32x4 zero = {0, 0, 0, 0};
  i32x4 acc[2][16];
  #pragma unroll
  for (int i = 0; i < 2; ++i)
    #pragma unroll
    for (int j = 0; j < 16; ++j) acc[i][j] = zero;

  const i8* Aqg = Aq + ((long)f*B_ + b0)*M_;
  const i8* Arg = Ar + ((long)f*B_ + b0)*M_;
  const i8* Bg  = cbT8 + ((long)f*D_ + d0)*M_;

  // per-wave DMA plan: 32 issues = Aq 8 + Ar 8 + B 16 windows(16 rows each);
  // wave takes 8. lane fetches global chunk (pl ^ ((rl>>1)&3)) so LDS slot c'
  // holds chunk c'^swz (matches read-side swizzle).
  const i8* gsrc[8];
  i8* lbase[8];
  int swz = (rl >> 1) & 3;
  #pragma unroll
  for (int j2 = 0; j2 < 8; ++j2){
    int job = j2*4 + wv;            // 0..31
    const i8* src; i8* lb; int jj;
    if (job < 8)      { src = Aqg; jj = job;      lb = smem +         jj*1024; }
    else if (job < 16){ src = Arg; jj = job - 8;  lb = smem +  8192 + jj*1024; }
    else              { src = Bg;  jj = job - 16; lb = smem + 16384 + jj*1024; }
    gsrc[j2]  = src + (long)(jj*16 + rl)*M_ + ((pl ^ swz) << 4);
    lbase[j2] = lb;                 // HW adds lane*16B
  }

  // prologue: issue kt=0 into buffer 0
  #pragma unroll
  for (int j2 = 0; j2 < 8; ++j2)
    gload_lds16(gsrc[j2], lbase[j2]);

  for (int kt = 0; kt < 8; ++kt){
    __syncthreads();   // drains buffer[kt&1]'s DMA; frees buffer[(kt+1)&1] reads
    if (kt < 7){
      int nb = (kt + 1) & 1, k0 = (kt + 1)*64;
      #pragma unroll
      for (int j2 = 0; j2 < 8; ++j2)
        gload_lds16(gsrc[j2] + k0, lbase[j2] + nb*SMSZ2);
    }
    const i8* sb = smem + (kt & 1)*SMSZ2;
    i32x4 aq[2], ar[2];
    #pragma unroll
    for (int rt = 0; rt < 2; ++rt){
      int row = wv*32 + rt*16 + l16;     // A[m=lane&15][k=quad*16+j]
      int c = (quad ^ ((row >> 1) & 3)) << 4;
      aq[rt] = *(const i32x4*)(sb +        row*64 + c);
      ar[rt] = *(const i32x4*)(sb + 8192 + row*64 + c);
    }
    __builtin_amdgcn_s_setprio(1);
    #pragma unroll
    for (int ct = 0; ct < 16; ++ct){
      int rowB = ct*16 + l16;            // B[k=quad*16+j][n=lane&15] via B^T tile
      int c = (quad ^ ((rowB >> 1) & 3)) << 4;
      i32x4 bb = *(const i32x4*)(sb + 16384 + rowB*64 + c);
      i32x4 bb64;
      #pragma unroll
      for (int g = 0; g < 4; ++g)
        bb64[g] = (int)(((u32)bb[g] << 6) & 0xC0C0C0C0u);   // 64*c, exact for c=+-1
      acc[0][ct] = __builtin_amdgcn_mfma_i32_16x16x64_i8(aq[0], bb64, acc[0][ct], 0, 0, 0);
      acc[0][ct] = __builtin_amdgcn_mfma_i32_16x16x64_i8(ar[0], bb,   acc[0][ct], 0, 0, 0);
      acc[1][ct] = __builtin_amdgcn_mfma_i32_16x16x64_i8(aq[1], bb64, acc[1][ct], 0, 0, 0);
      acc[1][ct] = __builtin_amdgcn_mfma_i32_16x16x64_i8(ar[1], bb,   acc[1][ct], 0, 0, 0);
    }
    __builtin_amdgcn_s_setprio(0);
  }

  // ballot epilogue: C/D layout col=lane&15, row=quad*4+reg. ballot bit(16q+t)
  // = sign at (row q*4+r, col ct*16+t). Row covers 256 d-cols = 4 u64 words.
  // Lane<16 holds word pw=lane&3 of row-quad q3=lane>>2. All sign-words
  // computed first, then batched old-estbits reads, one compare/write pass.
  int q3 = (lane >> 2) & 3, pw = lane & 3;
  int pw1 = pw & 1, pw2 = pw >> 1;
  u64 wreg[2][4];
  #pragma unroll
  for (int rt = 0; rt < 2; ++rt){
    #pragma unroll
    for (int r = 0; r < 4; ++r){
      u64 g0[4], g1[4], g2[4], g3[4];
      #pragma unroll
      for (int c = 0; c < 4; ++c){
        g0[c] = __ballot(acc[rt][c][r]      < 0);
        g1[c] = __ballot(acc[rt][4 + c][r]  < 0);
        g2[c] = __ballot(acc[rt][8 + c][r]  < 0);
        g3[c] = __ballot(acc[rt][12 + c][r] < 0);
      }
      u64 word = 0;
      #pragma unroll
      for (int c = 0; c < 4; ++c){
        u64 s = pw2 ? (pw1 ? g3[c] : g2[c]) : (pw1 ? g1[c] : g0[c]);
        word |= ((s >> (16*q3)) & 0xFFFFull) << (16*c);
      }
      wreg[rt][r] = word;
    }
  }
  u64 oldv[2][4];
  if (lane < 16){
    #pragma unroll
    for (int rt = 0; rt < 2; ++rt)
      #pragma unroll
      for (int r = 0; r < 4; ++r){
        int row = wv*32 + rt*16 + q3*4 + r;
        oldv[rt][r] = estbits[((long)(b0 + row)*F_ + f)*DW_ + dtp*4 + pw];
      }
  }
  u32 flag = 0;
  if (lane < 16){
    #pragma unroll
    for (int rt = 0; rt < 2; ++rt)
      #pragma unroll
      for (int r = 0; r < 4; ++r){
        int row = wv*32 + rt*16 + q3*4 + r;
        long addr = ((long)(b0 + row)*F_ + f)*DW_ + dtp*4 + pw;
        estbits[addr] = wreg[rt][r];
        flag |= (oldv[rt][r] != wreg[rt][r]) ? 1u : 0u;
      }
  }
  u32 mymiss = (u32)(__ballot(flag != 0) != 0ull);
  if (lane == 0 && mymiss) atomicAnd(&fl->conv[iter], 0u);
}

// final: outcome = argmax_m |sim|, first-occurrence ties (exact integers).
__global__ __launch_bounds__(256) void k_outcome(
    const u64* __restrict__ estbits, const u64* __restrict__ cbbT,
    const Flags* __restrict__ fl, float* __restrict__ out){
  __shared__ u64 es[8][DW_];
  __shared__ int redv[4][8], redi[4][8];
  int f = blockIdx.y, b0 = blockIdx.x * 8;
  int tid = threadIdx.x, wv = tid >> 6, lane = tid & 63;
  for (int idx = tid; idx < 8*DW_; idx += 256){
    int bb = idx >> 7, w = idx & 127;
    es[bb][w] = estbits[((long)(b0 + bb)*F_ + f)*DW_ + w];
  }
  __syncthreads();
  const u64* cbf = cbbT + (long)f*DW_*M_;
  int m0 = tid, m1 = tid + 256;
  int acc0[8], acc1[8];
  #pragma unroll
  for (int bb = 0; bb < 8; ++bb){ acc0[bb] = 0; acc1[bb] = 0; }
  for (int w = 0; w < DW_; ++w){
    u64 c0 = cbf[(long)w*M_ + m0];
    u64 c1 = cbf[(long)w*M_ + m1];
    #pragma unroll
    for (int bb = 0; bb < 8; ++bb){
      u64 e = es[bb][w];
      acc0[bb] += (int)__popcll(e ^ c0);
      acc1[bb] += (int)__popcll(e ^ c1);
    }
  }
  int bv[8], bi[8];
  #pragma unroll
  for (int bb = 0; bb < 8; ++bb){
    int a0 = 4096 - acc0[bb]; if (a0 < 0) a0 = -a0;
    int a1 = 4096 - acc1[bb]; if (a1 < 0) a1 = -a1;
    bv[bb] = a0; bi[bb] = m0;
    if (a1 > a0){ bv[bb] = a1; bi[bb] = m1; }   // tie keeps lower m
  }
  for (int off = 32; off; off >>= 1){
    #pragma unroll
    for (int bb = 0; bb < 8; ++bb){
      int ov = __shfl_xor(bv[bb], off, 64);
      int oi = __shfl_xor(bi[bb], off, 64);
      if (ov > bv[bb] || (ov == bv[bb] && oi < bi[bb])){ bv[bb] = ov; bi[bb] = oi; }
    }
  }
  if (lane == 0)
    #pragma unroll
    for (int bb = 0; bb < 8; ++bb){ redv[wv][bb] = bv[bb]; redi[wv][bb] = bi[bb]; }
  __syncthreads();
  if (tid < 8){
    int v0 = redv[0][tid], i0 = redi[0][tid];
    for (int w = 1; w < 4; ++w){
      int v = redv[w][tid], i = redi[w][tid];
      if (v > v0 || (v == v0 && i < i0)){ v0 = v; i0 = i; }
    }
    out[(long)(b0 + tid)*F_ + f] = (float)i0;
  }
  if (blockIdx.x == 0 && f == 0 && tid == 0){
    int k = ITERS_;
    for (int j = 0; j < ITERS_; ++j) if (fl->conv[j]){ k = j + 1; break; }
    out[B_*F_] = (float)k;
  }
}

__global__ void k_unpack(const u64* __restrict__ estbits, float* __restrict__ out){
  long gid = (long)blockIdx.x*256 + threadIdx.x;   // over B*F*D/4
  int bf = (int)(gid >> 11);
  int d4 = (int)(gid & 2047);
  u64 word = estbits[(long)bf*DW_ + (d4 >> 4)];
  u32 nib = (u32)(word >> ((d4 & 15) * 4)) & 0xFu;
  long base = (long)(B_*F_ + 1) + (long)bf*D_ + (long)d4*4;
  out[base+0] = (nib & 1u) ? -1.0f : 1.0f;
  out[base+1] = (nib & 2u) ? -1.0f : 1.0f;
  out[base+2] = (nib & 4u) ? -1.0f : 1.0f;
  out[base+3] = (nib & 8u) ? -1.0f : 1.0f;
}

extern "C" void kernel_launch(void* const* d_in, const int* in_sizes, int n_in,
                              void* d_out, int out_size, void* d_ws, size_t ws_size,
                              hipStream_t stream){
  const float* input    = (const float*)d_in[0];
  const float* init_est = (const float*)d_in[1];
  const float* cb       = (const float*)d_in[2];
  char* ws   = (char*)d_ws;
  char* outc = (char*)d_out;

  size_t off = 0;
  Flags* fl = (Flags*)(ws); off = 1024;
  u64* tmp0    = (u64*)(ws + off); off += (size_t)F_*DW_*8;        // 4 KB
  off = (off + 1023) & ~size_t(1023);
  u64* inbits  = (u64*)(ws + off); off += (size_t)B_*DW_*8;        // 1 MB
  u64* estbits = (u64*)(ws + off); off += (size_t)B_*F_*DW_*8;     // 4 MB
  u64* cbbT    = (u64*)(ws + off); off += (size_t)F_*DW_*M_*8;     // 2 MB
  size_t big = (size_t)F_*D_*M_ + 2*(size_t)F_*B_*M_;              // 16 MB + 4 MB
  i8 *cbT8, *Aq, *Ar;
  if (ws_size >= off + big + 1024){
    cbT8 = (i8*)(ws + off); off += (size_t)F_*D_*M_;
    Aq   = (i8*)(ws + off); off += (size_t)F_*B_*M_;
    Ar   = (i8*)(ws + off); off += (size_t)F_*B_*M_;
  } else {
    // d_out is 33558529 float32 = 128.02 MiB; est chunk spans [16388, 134234116).
    // Park scratch high — only the final k_unpack overwrites it, after last use.
    cbT8 = (i8*)(outc + (80ull << 20));    // 80..96 MiB
    Aq   = (i8*)(outc + (100ull << 20));   // 100..102 MiB
    Ar   = (i8*)(outc + (104ull << 20));   // 104..106 MiB
  }

  k_bitify0<<<(F_*D_)/256, 256, 0, stream>>>(init_est, tmp0, fl);
  k_bcast<<<(B_*F_*DW_)/256, 256, 0, stream>>>(tmp0, estbits);
  k_bitify<<<(B_*(long)D_)/256, 256, 0, stream>>>(input, inbits);
  k_cb_prep<<<4096, 256, 0, stream>>>(cb, cbbT, cbT8);

  for (int it = 0; it < ITERS_; ++it){
    k_forward2<<<1024, 256, 0, stream>>>(inbits, estbits, cbbT, Aq, Ar, fl, it);
    k_backward_d256<<<1024, 256, 0, stream>>>(Aq, Ar, cbT8, estbits, fl, it);
  }

  k_outcome<<<dim3(B_/8, F_), 256, 0, stream>>>(estbits, cbbT, fl, (float*)d_out);
  k_unpack<<<((long)B_*F_*D_/4)/256, 256, 0, stream>>>(estbits, (float*)d_out);
}

// Round 12
// 1387.382 us; speedup vs baseline: 1.0559x; 1.0120x over previous
//
#include <hip/hip_runtime.h>
#include <stdint.h>

#define B_ 1024
#define F_ 4
#define M_ 512
#define D_ 8192
#define ITERS_ 10
#define DW_ 128      // D/64 u64 words per D-vector
#define SMSZ2 32768  // one staging buffer: Aq 8K + Ar 8K + B 16K

typedef unsigned long long u64;
typedef unsigned int u32;
typedef unsigned short u16;
typedef signed char i8;

typedef int i32x4 __attribute__((ext_vector_type(4)));
typedef u64 u64x2 __attribute__((ext_vector_type(2)));

struct Flags { u32 done; u32 k; u32 conv[ITERS_]; };

__device__ inline void gload_lds16(const void* g, void* l){
  __builtin_amdgcn_global_load_lds(
      (const __attribute__((address_space(1))) void*)g,
      (__attribute__((address_space(3))) void*)l, 16, 0, 0);
}

__device__ inline bool conv_prefix_done(const u32* conv, int iter){
  bool d = false;
  for (int j = 0; j < iter; ++j) d |= (conv[j] != 0u);
  return d;
}

// sign-bit pack (bit=1 => negative) via wave ballot; one u64 per 64 floats
__global__ void k_bitify(const float* __restrict__ src, u64* __restrict__ dst){
  long gid = (long)blockIdx.x * 256 + threadIdx.x;
  float v = src[gid];
  u64 m = __ballot(v < 0.0f);
  if ((threadIdx.x & 63) == 0) dst[gid >> 6] = m;
}

// init_est is broadcast over b by construction; bitify row b=0 only + Flags init
__global__ void k_bitify0(const float* __restrict__ init_est, u64* __restrict__ tmp0,
                          Flags* fl){
  long gid = (long)blockIdx.x * 256 + threadIdx.x;   // over F_*D_
  float v = init_est[gid];
  u64 m = __ballot(v < 0.0f);
  if ((threadIdx.x & 63) == 0) tmp0[gid >> 6] = m;
  if (blockIdx.x == 0){
    if (threadIdx.x == 0){ fl->done = 0; fl->k = 0; }
    if (threadIdx.x < ITERS_) fl->conv[threadIdx.x] = 1u;
  }
}

// broadcast tmp0[f][w] to estbits[b][f][w] for all b
__global__ void k_bcast(const u64* __restrict__ tmp0, u64* __restrict__ estbits){
  long gid = (long)blockIdx.x * 256 + threadIdx.x;   // over B_*F_*DW_
  estbits[gid] = tmp0[gid & (F_*DW_ - 1)];
}

// one pass over cb: cbbT[f][w][m] (bit-packed) AND cbT8[f][d][m] (i8 +-1)
__global__ void k_cb_prep(const float* __restrict__ cb, u64* __restrict__ cbbT,
                          i8* __restrict__ cbT8){
  __shared__ i8 tile[64][68];
  int bx = blockIdx.x;
  int f = bx >> 10;
  int r = bx & 1023;
  int mt = r >> 7, dt = r & 127;
  for (int it = 0; it < 16; ++it){
    int lid = threadIdx.x + it*256;
    int i = lid >> 6, j = lid & 63;   // i = m-local (wave-uniform), j = d-local = lane
    float v = cb[((long)(f*M_ + mt*64 + i))*D_ + dt*64 + j];
    tile[j][i] = (v < 0.0f) ? (i8)-1 : (i8)1;
    u64 msk = __ballot(v < 0.0f);     // bit L = sign at d = dt*64 + L
    if (j == 0) cbbT[((long)(f*DW_ + dt))*M_ + mt*64 + i] = msk;
  }
  __syncthreads();
  for (int it = 0; it < 4; ++it){
    int lid = threadIdx.x + it*256;   // 1024 jobs: 64 d x 16 m-groups
    int dd = lid >> 4, mg = lid & 15;
    u32 p = (u32)(unsigned char)tile[dd][mg*4+0]
          | ((u32)(unsigned char)tile[dd][mg*4+1] << 8)
          | ((u32)(unsigned char)tile[dd][mg*4+2] << 16)
          | ((u32)(unsigned char)tile[dd][mg*4+3] << 24);
    *(u32*)(cbT8 + ((long)(f*D_ + dt*64 + dd))*M_ + mt*64 + mg*4) = p;
  }
}

// forward v2 (BEST measured config, R6 = 1395us): nb = in ^ (xor of other
// three est); v[m] = 4096 - popc(nb ^ cb[m]). Block = 8 b-rows x 256 m for
// one f (1024 blocks = 128 bt x 4 f x 2 mh; 16 waves/CU). Occupancy curve
// measured R8-R10: 8 waves 1465, 16 waves 1395, 30 waves 1438 -> optimum;
// prefetch-depth and LDS-request probes null. Structural floor for this
// decomposition.
__global__ __launch_bounds__(256) void k_forward2(
    const u64* __restrict__ inbits, const u64* __restrict__ estbits,
    const u64* __restrict__ cbbT, i8* __restrict__ Aq, i8* __restrict__ Ar,
    const Flags* __restrict__ fl, int iter){
  if (conv_prefix_done(fl->conv, iter)) return;
  __shared__ u64 nbs[DW_][10];   // [w][bb], pad 10 (16B-aligned bb-pairs)
  int id = blockIdx.x;
  int rr = id & 7;
  int f   = rr & 3;
  int btl = rr >> 2;
  int q   = id >> 3;
  int bth = q & 63;
  int mh  = q >> 6;              // 0..1
  int bt  = bth*2 + btl;         // 0..127
  int b0  = bt * 8;
  int tid = threadIdx.x;
  for (int idx = tid; idx < 8*DW_; idx += 256){
    int w = idx & 127, bb = idx >> 7;
    const u64* eb = estbits + (long)(b0 + bb)*F_*DW_;
    u64 all = eb[w] ^ eb[DW_+w] ^ eb[2*DW_+w] ^ eb[3*DW_+w];
    nbs[w][bb] = inbits[(long)(b0 + bb)*DW_ + w] ^ all ^ eb[f*DW_ + w];
  }
  __syncthreads();
  int m = mh*256 + tid;
  int acc[8];
  #pragma unroll
  for (int bb = 0; bb < 8; ++bb) acc[bb] = 0;
  const u64* cbf = cbbT + (long)f*DW_*M_ + m;
  #pragma unroll 2
  for (int w = 0; w < DW_; ++w){
    u64 c = cbf[(long)w*M_];
    u64x2 n01 = *(const u64x2*)&nbs[w][0];
    u64x2 n23 = *(const u64x2*)&nbs[w][2];
    u64x2 n45 = *(const u64x2*)&nbs[w][4];
    u64x2 n67 = *(const u64x2*)&nbs[w][6];
    acc[0] += (int)__popcll(n01.x ^ c);
    acc[1] += (int)__popcll(n01.y ^ c);
    acc[2] += (int)__popcll(n23.x ^ c);
    acc[3] += (int)__popcll(n23.y ^ c);
    acc[4] += (int)__popcll(n45.x ^ c);
    acc[5] += (int)__popcll(n45.y ^ c);
    acc[6] += (int)__popcll(n67.x ^ c);
    acc[7] += (int)__popcll(n67.y ^ c);
  }
  #pragma unroll
  for (int bb = 0; bb < 8; ++bb){
    int v = 4096 - acc[bb];
    int r = ((v + 32) & 63) - 32;
    int qd = (v - r) >> 6;
    long base = ((long)(f*B_ + b0 + bb))*M_ + m;
    Aq[base] = (i8)qd;
    Ar[base] = (i8)r;
  }
}

// backward (VERIFIED best, R5/R6 = 1395us): y[b][d] = sum q*(64c) + sum r*c,
// exact. i8 MFMA 16x16x64, double-buffered DMA, d-tile 256. __syncthreads per
// kt is the correct sync (vmcnt is per-wave; cross-wave DMA-complete must flow
// through the barrier drain). Measured-null levers: counted-vmcnt (racy at
// this LDS capacity), setprio (R11: 1404 vs 1395). Remaining gap to the
// ~32us arithmetic floor is the barrier-drain structure itself.
// f-partitioned XCD grid: id%8 = f*2 + (d-half); 1024 blocks.
__global__ __launch_bounds__(256, 2) void k_backward_d256(
    const i8* __restrict__ Aq, const i8* __restrict__ Ar, const i8* __restrict__ cbT8,
    u64* __restrict__ estbits, Flags* fl, int iter){
  if (conv_prefix_done(fl->conv, iter)) return;
  __shared__ __attribute__((aligned(16))) i8 smem[2*SMSZ2]; // 65536 B
  int id = blockIdx.x;
  int rr = id & 7;
  int f  = rr >> 1;
  int dh = rr & 1;
  int qq = id >> 3;
  int bt = qq & 7;
  int dtl= qq >> 3;           // 0..15
  int dtp= dh*16 + dtl;       // 0..31 (256-wide d tiles)
  int b0 = bt*128, d0 = dtp*256;
  int tid = threadIdx.x;
  int wv = tid >> 6, lane = tid & 63, l16 = lane & 15, quad = lane >> 4;
  int rl = lane >> 2, pl = lane & 3;   // DMA: 4 lanes per 64B row

  i32x4 zero = {0, 0, 0, 0};
  i32x4 acc[2][16];
  #pragma unroll
  for (int i = 0; i < 2; ++i)
    #pragma unroll
    for (int j = 0; j < 16; ++j) acc[i][j] = zero;

  const i8* Aqg = Aq + ((long)f*B_ + b0)*M_;
  const i8* Arg = Ar + ((long)f*B_ + b0)*M_;
  const i8* Bg  = cbT8 + ((long)f*D_ + d0)*M_;

  // per-wave DMA plan: 32 issues = Aq 8 + Ar 8 + B 16 windows(16 rows each);
  // wave takes 8. lane fetches global chunk (pl ^ ((rl>>1)&3)) so LDS slot c'
  // holds chunk c'^swz (matches read-side swizzle).
  const i8* gsrc[8];
  i8* lbase[8];
  int swz = (rl >> 1) & 3;
  #pragma unroll
  for (int j2 = 0; j2 < 8; ++j2){
    int job = j2*4 + wv;            // 0..31
    const i8* src; i8* lb; int jj;
    if (job < 8)      { src = Aqg; jj = job;      lb = smem +         jj*1024; }
    else if (job < 16){ src = Arg; jj = job - 8;  lb = smem +  8192 + jj*1024; }
    else              { src = Bg;  jj = job - 16; lb = smem + 16384 + jj*1024; }
    gsrc[j2]  = src + (long)(jj*16 + rl)*M_ + ((pl ^ swz) << 4);
    lbase[j2] = lb;                 // HW adds lane*16B
  }

  // prologue: issue kt=0 into buffer 0
  #pragma unroll
  for (int j2 = 0; j2 < 8; ++j2)
    gload_lds16(gsrc[j2], lbase[j2]);

  for (int kt = 0; kt < 8; ++kt){
    __syncthreads();   // drains buffer[kt&1]'s DMA; frees buffer[(kt+1)&1] reads
    if (kt < 7){
      int nb = (kt + 1) & 1, k0 = (kt + 1)*64;
      #pragma unroll
      for (int j2 = 0; j2 < 8; ++j2)
        gload_lds16(gsrc[j2] + k0, lbase[j2] + nb*SMSZ2);
    }
    const i8* sb = smem + (kt & 1)*SMSZ2;
    i32x4 aq[2], ar[2];
    #pragma unroll
    for (int rt = 0; rt < 2; ++rt){
      int row = wv*32 + rt*16 + l16;     // A[m=lane&15][k=quad*16+j]
      int c = (quad ^ ((row >> 1) & 3)) << 4;
      aq[rt] = *(const i32x4*)(sb +        row*64 + c);
      ar[rt] = *(const i32x4*)(sb + 8192 + row*64 + c);
    }
    #pragma unroll
    for (int ct = 0; ct < 16; ++ct){
      int rowB = ct*16 + l16;            // B[k=quad*16+j][n=lane&15] via B^T tile
      int c = (quad ^ ((rowB >> 1) & 3)) << 4;
      i32x4 bb = *(const i32x4*)(sb + 16384 + rowB*64 + c);
      i32x4 bb64;
      #pragma unroll
      for (int g = 0; g < 4; ++g)
        bb64[g] = (int)(((u32)bb[g] << 6) & 0xC0C0C0C0u);   // 64*c, exact for c=+-1
      acc[0][ct] = __builtin_amdgcn_mfma_i32_16x16x64_i8(aq[0], bb64, acc[0][ct], 0, 0, 0);
      acc[0][ct] = __builtin_amdgcn_mfma_i32_16x16x64_i8(ar[0], bb,   acc[0][ct], 0, 0, 0);
      acc[1][ct] = __builtin_amdgcn_mfma_i32_16x16x64_i8(aq[1], bb64, acc[1][ct], 0, 0, 0);
      acc[1][ct] = __builtin_amdgcn_mfma_i32_16x16x64_i8(ar[1], bb,   acc[1][ct], 0, 0, 0);
    }
  }

  // ballot epilogue: C/D layout col=lane&15, row=quad*4+reg. ballot bit(16q+t)
  // = sign at (row q*4+r, col ct*16+t). Row covers 256 d-cols = 4 u64 words.
  // Lane<16 holds word pw=lane&3 of row-quad q3=lane>>2. All sign-words
  // computed first, then batched old-estbits reads, one compare/write pass.
  int q3 = (lane >> 2) & 3, pw = lane & 3;
  int pw1 = pw & 1, pw2 = pw >> 1;
  u64 wreg[2][4];
  #pragma unroll
  for (int rt = 0; rt < 2; ++rt){
    #pragma unroll
    for (int r = 0; r < 4; ++r){
      u64 g0[4], g1[4], g2[4], g3[4];
      #pragma unroll
      for (int c = 0; c < 4; ++c){
        g0[c] = __ballot(acc[rt][c][r]      < 0);
        g1[c] = __ballot(acc[rt][4 + c][r]  < 0);
        g2[c] = __ballot(acc[rt][8 + c][r]  < 0);
        g3[c] = __ballot(acc[rt][12 + c][r] < 0);
      }
      u64 word = 0;
      #pragma unroll
      for (int c = 0; c < 4; ++c){
        u64 s = pw2 ? (pw1 ? g3[c] : g2[c]) : (pw1 ? g1[c] : g0[c]);
        word |= ((s >> (16*q3)) & 0xFFFFull) << (16*c);
      }
      wreg[rt][r] = word;
    }
  }
  u64 oldv[2][4];
  if (lane < 16){
    #pragma unroll
    for (int rt = 0; rt < 2; ++rt)
      #pragma unroll
      for (int r = 0; r < 4; ++r){
        int row = wv*32 + rt*16 + q3*4 + r;
        oldv[rt][r] = estbits[((long)(b0 + row)*F_ + f)*DW_ + dtp*4 + pw];
      }
  }
  u32 flag = 0;
  if (lane < 16){
    #pragma unroll
    for (int rt = 0; rt < 2; ++rt)
      #pragma unroll
      for (int r = 0; r < 4; ++r){
        int row = wv*32 + rt*16 + q3*4 + r;
        long addr = ((long)(b0 + row)*F_ + f)*DW_ + dtp*4 + pw;
        estbits[addr] = wreg[rt][r];
        flag |= (oldv[rt][r] != wreg[rt][r]) ? 1u : 0u;
      }
  }
  u32 mymiss = (u32)(__ballot(flag != 0) != 0ull);
  if (lane == 0 && mymiss) atomicAnd(&fl->conv[iter], 0u);
}

// final: outcome = argmax_m |sim|, first-occurrence ties (exact integers).
__global__ __launch_bounds__(256) void k_outcome(
    const u64* __restrict__ estbits, const u64* __restrict__ cbbT,
    const Flags* __restrict__ fl, float* __restrict__ out){
  __shared__ u64 es[8][DW_];
  __shared__ int redv[4][8], redi[4][8];
  int f = blockIdx.y, b0 = blockIdx.x * 8;
  int tid = threadIdx.x, wv = tid >> 6, lane = tid & 63;
  for (int idx = tid; idx < 8*DW_; idx += 256){
    int bb = idx >> 7, w = idx & 127;
    es[bb][w] = estbits[((long)(b0 + bb)*F_ + f)*DW_ + w];
  }
  __syncthreads();
  const u64* cbf = cbbT + (long)f*DW_*M_;
  int m0 = tid, m1 = tid + 256;
  int acc0[8], acc1[8];
  #pragma unroll
  for (int bb = 0; bb < 8; ++bb){ acc0[bb] = 0; acc1[bb] = 0; }
  for (int w = 0; w < DW_; ++w){
    u64 c0 = cbf[(long)w*M_ + m0];
    u64 c1 = cbf[(long)w*M_ + m1];
    #pragma unroll
    for (int bb = 0; bb < 8; ++bb){
      u64 e = es[bb][w];
      acc0[bb] += (int)__popcll(e ^ c0);
      acc1[bb] += (int)__popcll(e ^ c1);
    }
  }
  int bv[8], bi[8];
  #pragma unroll
  for (int bb = 0; bb < 8; ++bb){
    int a0 = 4096 - acc0[bb]; if (a0 < 0) a0 = -a0;
    int a1 = 4096 - acc1[bb]; if (a1 < 0) a1 = -a1;
    bv[bb] = a0; bi[bb] = m0;
    if (a1 > a0){ bv[bb] = a1; bi[bb] = m1; }   // tie keeps lower m
  }
  for (int off = 32; off; off >>= 1){
    #pragma unroll
    for (int bb = 0; bb < 8; ++bb){
      int ov = __shfl_xor(bv[bb], off, 64);
      int oi = __shfl_xor(bi[bb], off, 64);
      if (ov > bv[bb] || (ov == bv[bb] && oi < bi[bb])){ bv[bb] = ov; bi[bb] = oi; }
    }
  }
  if (lane == 0)
    #pragma unroll
    for (int bb = 0; bb < 8; ++bb){ redv[wv][bb] = bv[bb]; redi[wv][bb] = bi[bb]; }
  __syncthreads();
  if (tid < 8){
    int v0 = redv[0][tid], i0 = redi[0][tid];
    for (int w = 1; w < 4; ++w){
      int v = redv[w][tid], i = redi[w][tid];
      if (v > v0 || (v == v0 && i < i0)){ v0 = v; i0 = i; }
    }
    out[(long)(b0 + tid)*F_ + f] = (float)i0;
  }
  if (blockIdx.x == 0 && f == 0 && tid == 0){
    int k = ITERS_;
    for (int j = 0; j < ITERS_; ++j) if (fl->conv[j]){ k = j + 1; break; }
    out[B_*F_] = (float)k;
  }
}

__global__ void k_unpack(const u64* __restrict__ estbits, float* __restrict__ out){
  long gid = (long)blockIdx.x*256 + threadIdx.x;   // over B*F*D/4
  int bf = (int)(gid >> 11);
  int d4 = (int)(gid & 2047);
  u64 word = estbits[(long)bf*DW_ + (d4 >> 4)];
  u32 nib = (u32)(word >> ((d4 & 15) * 4)) & 0xFu;
  long base = (long)(B_*F_ + 1) + (long)bf*D_ + (long)d4*4;
  out[base+0] = (nib & 1u) ? -1.0f : 1.0f;
  out[base+1] = (nib & 2u) ? -1.0f : 1.0f;
  out[base+2] = (nib & 4u) ? -1.0f : 1.0f;
  out[base+3] = (nib & 8u) ? -1.0f : 1.0f;
}

extern "C" void kernel_launch(void* const* d_in, const int* in_sizes, int n_in,
                              void* d_out, int out_size, void* d_ws, size_t ws_size,
                              hipStream_t stream){
  const float* input    = (const float*)d_in[0];
  const float* init_est = (const float*)d_in[1];
  const float* cb       = (const float*)d_in[2];
  char* ws   = (char*)d_ws;
  char* outc = (char*)d_out;

  size_t off = 0;
  Flags* fl = (Flags*)(ws); off = 1024;
  u64* tmp0    = (u64*)(ws + off); off += (size_t)F_*DW_*8;        // 4 KB
  off = (off + 1023) & ~size_t(1023);
  u64* inbits  = (u64*)(ws + off); off += (size_t)B_*DW_*8;        // 1 MB
  u64* estbits = (u64*)(ws + off); off += (size_t)B_*F_*DW_*8;     // 4 MB
  u64* cbbT    = (u64*)(ws + off); off += (size_t)F_*DW_*M_*8;     // 2 MB
  size_t big = (size_t)F_*D_*M_ + 2*(size_t)F_*B_*M_;              // 16 MB + 4 MB
  i8 *cbT8, *Aq, *Ar;
  if (ws_size >= off + big + 1024){
    cbT8 = (i8*)(ws + off); off += (size_t)F_*D_*M_;
    Aq   = (i8*)(ws + off); off += (size_t)F_*B_*M_;
    Ar   = (i8*)(ws + off); off += (size_t)F_*B_*M_;
  } else {
    // d_out is 33558529 float32 = 128.02 MiB; est chunk spans [16388, 134234116).
    // Park scratch high — only the final k_unpack overwrites it, after last use.
    cbT8 = (i8*)(outc + (80ull << 20));    // 80..96 MiB
    Aq   = (i8*)(outc + (100ull << 20));   // 100..102 MiB
    Ar   = (i8*)(outc + (104ull << 20));   // 104..106 MiB
  }

  k_bitify0<<<(F_*D_)/256, 256, 0, stream>>>(init_est, tmp0, fl);
  k_bcast<<<(B_*F_*DW_)/256, 256, 0, stream>>>(tmp0, estbits);
  k_bitify<<<(B_*(long)D_)/256, 256, 0, stream>>>(input, inbits);
  k_cb_prep<<<4096, 256, 0, stream>>>(cb, cbbT, cbT8);

  for (int it = 0; it < ITERS_; ++it){
    k_forward2<<<1024, 256, 0, stream>>>(inbits, estbits, cbbT, Aq, Ar, fl, it);
    k_backward_d256<<<1024, 256, 0, stream>>>(Aq, Ar, cbT8, estbits, fl, it);
  }

  k_outcome<<<dim3(B_/8, F_), 256, 0, stream>>>(estbits, cbbT, fl, (float*)d_out);
  k_unpack<<<((long)B_*F_*D_/4)/256, 256, 0, stream>>>(estbits, (float*)d_out);
}